// Round 6
// baseline (167.798 us; speedup 1.0000x reference)
//
#include <hip/hip_runtime.h>
#include <hip/hip_bf16.h>

#define B_ 4
#define H_ 16
#define N_ 2048
#define D_ 64
#define BM 128   // q-rows per WG (32 per wave, 4 waves)

typedef __bf16 bf16;
typedef bf16 bf16x4 __attribute__((ext_vector_type(4)));
typedef bf16 bf16x8 __attribute__((ext_vector_type(8)));
typedef float f32x16 __attribute__((ext_vector_type(16)));
typedef unsigned u32x2 __attribute__((ext_vector_type(2)));
typedef unsigned u32x4 __attribute__((ext_vector_type(4)));

#define SCALE_LOG2E 0.18033688011112042f  // (1/sqrt(64)) * log2(e)

// Per (b, kv-tile T of 64): 16 KB image in per-lane FRAGMENT ORDER for 32x32x16 MFMA.
//   K half  [0,8KB):  unit p=(mt*4+ks)*64+ln : A-frag K[kv=T*64+mt*32+(ln&31)][d=ks*16+(ln>>5)*8 ..+8]
//   V half  [8,16KB): unit p=(mt*4+ks)*64+ln : A-frag V^T[d=mt*32+(ln&31)][kv=T*64+ks*16+(ln>>5)*8 ..+8]
// V transpose via LDS: coalesced float4 row reads -> padded LDS -> fragment-order
// reads -> coalesced bf16x8 store. One block per tile.
__global__ __launch_bounds__(512) void convert_kv(const float* __restrict__ k,
                                                  const float* __restrict__ v,
                                                  bf16* __restrict__ img) {
    __shared__ bf16 VT[64][66];                   // stride 66 elems (132 B)
    const int tile = blockIdx.x;                  // b*32 + T
    const int b = tile >> 5, T = tile & 31;
    const int t = threadIdx.x;                    // 0..511 == unit id
    bf16* timg = img + (size_t)tile * 8192;       // 16 KB per tile

    const int mtks = t >> 6;
    const int ln   = t & 63;
    const int mt = mtks >> 2, ks = mtks & 3;

    // --- K half: direct, coalesced both sides ---
    {
        const int kvr = T * 64 + mt * 32 + (ln & 31);
        const int d0  = ks * 16 + (ln >> 5) * 8;
        const float* src = k + ((size_t)b * N_ + kvr) * D_ + d0;
        float4 a = *(const float4*)src;
        float4 c = *(const float4*)(src + 4);
        bf16x8 o;
        o[0] = (bf16)a.x; o[1] = (bf16)a.y; o[2] = (bf16)a.z; o[3] = (bf16)a.w;
        o[4] = (bf16)c.x; o[5] = (bf16)c.y; o[6] = (bf16)c.z; o[7] = (bf16)c.w;
        *(bf16x8*)(timg + t * 8) = o;
    }

    // --- V half phase 1: coalesced row load -> LDS bf16 ---
    {
        const int kv = t >> 3;                    // 0..63 (tile-local row)
        const int c8 = (t & 7) * 8;               // 0..56
        const float* src = v + ((size_t)b * N_ + T * 64 + kv) * D_ + c8;
        float4 a = *(const float4*)src;
        float4 c = *(const float4*)(src + 4);
        VT[kv][c8 + 0] = (bf16)a.x; VT[kv][c8 + 1] = (bf16)a.y;
        VT[kv][c8 + 2] = (bf16)a.z; VT[kv][c8 + 3] = (bf16)a.w;
        VT[kv][c8 + 4] = (bf16)c.x; VT[kv][c8 + 5] = (bf16)c.y;
        VT[kv][c8 + 6] = (bf16)c.z; VT[kv][c8 + 7] = (bf16)c.w;
    }
    __syncthreads();
    // --- V half phase 2: fragment-order read, coalesced store ---
    {
        const int d   = mt * 32 + (ln & 31);
        const int kv0 = ks * 16 + (ln >> 5) * 8;  // tile-local
        bf16x8 o;
        #pragma unroll
        for (int j = 0; j < 8; ++j) o[j] = VT[kv0 + j][d];
        *(bf16x8*)(timg + 4096 + t * 8) = o;
    }
}

static __device__ inline bf16x4 pack4(float a, float b, float c, float d) {
    bf16x4 r; r[0] = (bf16)a; r[1] = (bf16)b; r[2] = (bf16)c; r[3] = (bf16)d; return r;
}

// C->B half-wave exchange via v_permlane32_swap_b32. For (p,q) = swap(L,H):
//   p = {L.row0, H.row0}  == (half ? xhi : lo)
//   q = {L.row1, H.row1}  == (half ? hi  : xlo)
static __device__ inline bf16x8 cswap(bf16x4 lo, bf16x4 hi) {
    u32x2 l = __builtin_bit_cast(u32x2, lo);
    u32x2 h = __builtin_bit_cast(u32x2, hi);
    u32x2 r0 = __builtin_amdgcn_permlane32_swap(l[0], h[0], false, false);
    u32x2 r1 = __builtin_amdgcn_permlane32_swap(l[1], h[1], false, false);
    u32x4 o; o[0] = r0[0]; o[1] = r1[0]; o[2] = r0[1]; o[3] = r1[1];
    return __builtin_bit_cast(bf16x8, o);
}

// Flash attention, 32x32x16 MFMA, S^T/O^T orientation, P in registers.
//
// Round-6: R5's barrier-free global-streaming base + FULL in-register
// double-buffer of K/V fragments (named A/B sets, unroll-2; rule #20 says
// no runtime-indexed reg arrays). Loads for tile t+1 are issued BEFORE the
// body of tile t, so the compiler emits counted vmcnt waits (T4) and each
// load has a full iteration (~900 cy of issue) to cover L2 latency.
// Evidence: R0/R3/R5 all pin at ~90 us with VALUBusy<=44% regardless of
// occupancy and barriers -> the binder is zero-issue-distance load->use
// chains stalling all (phase-correlated) waves together.
// Register budget ~220 unified -> launch_bounds(256,2): 2 waves/SIMD
// (R0 proved 2/SIMD == 4/SIMD here; stall-free waves need less TLP).
__global__ __launch_bounds__(256, 2) void attn_fwd(const float* __restrict__ q,
                                                   const bf16* __restrict__ img,
                                                   float* __restrict__ out) {
    const int tid  = threadIdx.x;
    const int lane = tid & 63;
    const int wv   = tid >> 6;          // 0..3
    const int half = lane >> 5;
    const int l31  = lane & 31;

    const int bh = blockIdx.y;
    const int b  = bh >> 4;
    const int q0 = blockIdx.x * BM + wv * 32;

    const bf16* tiles = img + (size_t)b * 32 * 8192;

    // Q frags (B-layout for S^T: n=q=l31, k=d=ks*16+half*8+j), pre-scaled
    bf16x8 qf[4];
    #pragma unroll
    for (int ks = 0; ks < 4; ++ks) {
        const float* src = q + ((size_t)bh * N_ + q0 + l31) * D_ + ks * 16 + half * 8;
        float4 a = *(const float4*)src;
        float4 c = *(const float4*)(src + 4);
        bf16x8 pk;
        pk[0] = (bf16)(a.x * SCALE_LOG2E); pk[1] = (bf16)(a.y * SCALE_LOG2E);
        pk[2] = (bf16)(a.z * SCALE_LOG2E); pk[3] = (bf16)(a.w * SCALE_LOG2E);
        pk[4] = (bf16)(c.x * SCALE_LOG2E); pk[5] = (bf16)(c.y * SCALE_LOG2E);
        pk[6] = (bf16)(c.z * SCALE_LOG2E); pk[7] = (bf16)(c.w * SCALE_LOG2E);
        qf[ks] = pk;
    }

    f32x16 acc[2] = {{}, {}};           // O^T tiles [mt_d] (unnormalized)
    float lacc = 0.f;

    // fragment loaders: 8 coalesced 16B/lane loads each (frag u = mt*4+ks)
    auto loadK = [&](int it, bf16x8 (&kf)[8]) {
        const bf16* tp = tiles + (size_t)it * 8192;
        #pragma unroll
        for (int u = 0; u < 8; ++u)
            kf[u] = *(const bf16x8*)(tp + ((size_t)(u * 64 + lane)) * 8);
    };
    auto loadV = [&](int it, bf16x8 (&vf)[8]) {
        const bf16* tp = tiles + (size_t)it * 8192 + 4096;
        #pragma unroll
        for (int u = 0; u < 8; ++u)
            vf[u] = *(const bf16x8*)(tp + ((size_t)(u * 64 + lane)) * 8);
    };

    // S^T = K Q^T -> exp2 -> C->B swap -> O^T += V^T P^T
    auto body = [&](const bf16x8 (&kf)[8], const bf16x8 (&vf)[8]) {
        f32x16 s[2] = {{}, {}};
        #pragma unroll
        for (int ks = 0; ks < 4; ++ks) {
            s[0] = __builtin_amdgcn_mfma_f32_32x32x16_bf16(kf[0 * 4 + ks], qf[ks], s[0], 0, 0, 0);
            s[1] = __builtin_amdgcn_mfma_f32_32x32x16_bf16(kf[1 * 4 + ks], qf[ks], s[1], 0, 0, 0);
        }
        #pragma unroll
        for (int mt = 0; mt < 2; ++mt) {
            float pv[16];
            #pragma unroll
            for (int r = 0; r < 16; ++r) pv[r] = __builtin_amdgcn_exp2f(s[mt][r]);
            float t0s = 0.f, t1s = 0.f;
            #pragma unroll
            for (int r = 0; r < 8; ++r) { t0s += pv[r]; t1s += pv[8 + r]; }
            lacc += t0s + t1s;
            #pragma unroll
            for (int sp = 0; sp < 2; ++sp) {
                bf16x4 lo = pack4(pv[8 * sp + 0], pv[8 * sp + 1], pv[8 * sp + 2], pv[8 * sp + 3]);
                bf16x4 hi = pack4(pv[8 * sp + 4], pv[8 * sp + 5], pv[8 * sp + 6], pv[8 * sp + 7]);
                bf16x8 bfrag = cswap(lo, hi);
                const int g = mt * 2 + sp;        // kv k-step 0..3
                acc[0] = __builtin_amdgcn_mfma_f32_32x32x16_bf16(vf[0 * 4 + g], bfrag, acc[0], 0, 0, 0);
                acc[1] = __builtin_amdgcn_mfma_f32_32x32x16_bf16(vf[1 * 4 + g], bfrag, acc[1], 0, 0, 0);
            }
        }
    };

    bf16x8 kfA[8], vfA[8], kfB[8], vfB[8];
    loadK(0, kfA); loadV(0, vfA);

    #pragma unroll 1
    for (int it = 0; it < 32; it += 2) {
        loadK(it + 1, kfB); loadV(it + 1, vfB);   // prefetch odd tile
        body(kfA, vfA);                            // compute even tile
        if (it + 2 < 32) { loadK(it + 2, kfA); loadV(it + 2, vfA); }  // prefetch next even
        body(kfB, vfB);                            // compute odd tile
    }

    // epilogue: denominator = own + partner half-wave partial; store float4
    float l = lacc + __shfl_xor(lacc, 32);
    float inv = 1.0f / l;
    const int qrow = q0 + l31;
    float* dst = out + ((size_t)bh * N_ + qrow) * D_ + 4 * half;
    #pragma unroll
    for (int mt = 0; mt < 2; ++mt)
        #pragma unroll
        for (int rq = 0; rq < 4; ++rq) {
            float4 o;
            o.x = acc[mt][4 * rq + 0] * inv;
            o.y = acc[mt][4 * rq + 1] * inv;
            o.z = acc[mt][4 * rq + 2] * inv;
            o.w = acc[mt][4 * rq + 3] * inv;
            *(float4*)(dst + mt * 32 + 8 * rq) = o;   // d = mt*32 + 8*rq + 4*half
        }
}

extern "C" void kernel_launch(void* const* d_in, const int* in_sizes, int n_in,
                              void* d_out, int out_size, void* d_ws, size_t ws_size,
                              hipStream_t stream) {
    const float* q = (const float*)d_in[0];
    const float* k = (const float*)d_in[1];
    const float* v = (const float*)d_in[2];
    float* out = (float*)d_out;

    bf16* img = (bf16*)d_ws;                      // 128 tiles x 16 KB = 2 MB

    convert_kv<<<B_ * 32, 512, 0, stream>>>(k, v, img);
    dim3 grid(N_ / BM, B_ * H_);
    attn_fwd<<<grid, 256, 0, stream>>>(q, img, out);
}

// Round 7
// 156.267 us; speedup vs baseline: 1.0738x; 1.0738x over previous
//
#include <hip/hip_runtime.h>
#include <hip/hip_bf16.h>

#define B_ 4
#define H_ 16
#define N_ 2048
#define D_ 64
#define BM 128   // q-rows per WG (32 per wave, 4 wave-pairs)
#define BN 64    // kv per iter per group

typedef __bf16 bf16;
typedef bf16 bf16x4 __attribute__((ext_vector_type(4)));
typedef bf16 bf16x8 __attribute__((ext_vector_type(8)));
typedef float f32x16 __attribute__((ext_vector_type(16)));
typedef unsigned u32x2 __attribute__((ext_vector_type(2)));
typedef unsigned u32x4 __attribute__((ext_vector_type(4)));

#define SCALE_LOG2E 0.18033688011112042f  // (1/sqrt(64)) * log2(e)

#define GBL(p) ((const __attribute__((address_space(1))) void*)(p))
#define LDS(p) ((__attribute__((address_space(3))) void*)(p))

// Per (b, kv-tile T of 64): 16 KB image in per-lane FRAGMENT ORDER for 32x32x16 MFMA.
//   K half  [0,8KB):  unit p=(mt*4+ks)*64+ln : A-frag K[kv=T*64+mt*32+(ln&31)][d=ks*16+(ln>>5)*8 ..+8]
//   V half  [8,16KB): unit p=(mt*4+ks)*64+ln : A-frag V^T[d=mt*32+(ln&31)][kv=T*64+ks*16+(ln>>5)*8 ..+8]
// V transpose via LDS: coalesced float4 row reads -> padded LDS -> fragment-order
// reads -> coalesced bf16x8 store. One block per tile.
__global__ __launch_bounds__(512) void convert_kv(const float* __restrict__ k,
                                                  const float* __restrict__ v,
                                                  bf16* __restrict__ img) {
    __shared__ bf16 VT[64][66];                   // stride 66 elems (132 B)
    const int tile = blockIdx.x;                  // b*32 + T
    const int b = tile >> 5, T = tile & 31;
    const int t = threadIdx.x;                    // 0..511 == unit id
    bf16* timg = img + (size_t)tile * 8192;       // 16 KB per tile

    const int mtks = t >> 6;
    const int ln   = t & 63;
    const int mt = mtks >> 2, ks = mtks & 3;

    // --- K half: direct, coalesced both sides ---
    {
        const int kvr = T * 64 + mt * 32 + (ln & 31);
        const int d0  = ks * 16 + (ln >> 5) * 8;
        const float* src = k + ((size_t)b * N_ + kvr) * D_ + d0;
        float4 a = *(const float4*)src;
        float4 c = *(const float4*)(src + 4);
        bf16x8 o;
        o[0] = (bf16)a.x; o[1] = (bf16)a.y; o[2] = (bf16)a.z; o[3] = (bf16)a.w;
        o[4] = (bf16)c.x; o[5] = (bf16)c.y; o[6] = (bf16)c.z; o[7] = (bf16)c.w;
        *(bf16x8*)(timg + t * 8) = o;
    }

    // --- V half phase 1: coalesced row load -> LDS bf16 ---
    {
        const int kv = t >> 3;                    // 0..63 (tile-local row)
        const int c8 = (t & 7) * 8;               // 0..56
        const float* src = v + ((size_t)b * N_ + T * 64 + kv) * D_ + c8;
        float4 a = *(const float4*)src;
        float4 c = *(const float4*)(src + 4);
        VT[kv][c8 + 0] = (bf16)a.x; VT[kv][c8 + 1] = (bf16)a.y;
        VT[kv][c8 + 2] = (bf16)a.z; VT[kv][c8 + 3] = (bf16)a.w;
        VT[kv][c8 + 4] = (bf16)c.x; VT[kv][c8 + 5] = (bf16)c.y;
        VT[kv][c8 + 6] = (bf16)c.z; VT[kv][c8 + 7] = (bf16)c.w;
    }
    __syncthreads();
    // --- V half phase 2: fragment-order read, coalesced store ---
    {
        const int d   = mt * 32 + (ln & 31);
        const int kv0 = ks * 16 + (ln >> 5) * 8;  // tile-local
        bf16x8 o;
        #pragma unroll
        for (int j = 0; j < 8; ++j) o[j] = VT[kv0 + j][d];
        *(bf16x8*)(timg + 4096 + t * 8) = o;
    }
}

static __device__ inline bf16x4 pack4(float a, float b, float c, float d) {
    bf16x4 r; r[0] = (bf16)a; r[1] = (bf16)b; r[2] = (bf16)c; r[3] = (bf16)d; return r;
}

// C->B half-wave exchange via v_permlane32_swap_b32. For (p,q) = swap(L,H):
//   p = {L.row0, H.row0}  == (half ? xhi : lo)
//   q = {L.row1, H.row1}  == (half ? hi  : xlo)
static __device__ inline bf16x8 cswap(bf16x4 lo, bf16x4 hi) {
    u32x2 l = __builtin_bit_cast(u32x2, lo);
    u32x2 h = __builtin_bit_cast(u32x2, hi);
    u32x2 r0 = __builtin_amdgcn_permlane32_swap(l[0], h[0], false, false);
    u32x2 r1 = __builtin_amdgcn_permlane32_swap(l[1], h[1], false, false);
    u32x4 o; o[0] = r0[0]; o[1] = r1[0]; o[2] = r0[1]; o[3] = r1[1];
    return __builtin_bit_cast(bf16x8, o);
}

// Flash attention, 32x32x16 MFMA, S^T/O^T orientation, P in registers.
// 8 waves/block: waves 0-3 (grp 0) process KV tiles 0..15, waves 4-7 (grp 1)
// tiles 16..31, for the SAME 128 q-rows; each wave owns 32 q-rows.
//
// Round-7 changes (evidence R0-R6: ~90us plateau invariant to occupancy,
// memory source, prefetch depth -> binder is phase-correlated dependency
// stalls + long single-pipe bursts):
//  (1) denominator via ones-row MFMA (accL): kills the 34-add reduction,
//      lacc, and the epilogue shfl (the MFMA sums all 16 k-rows for every
//      q-col; all accumulator rows identical). +4 MFMA/iter on idle pipe.
//  (2) fine-grained pipe mixing: exp2 moved into the sp-loop so each chunk
//      is {8 exp2, 2 pack, 2 permlane, 3 MFMA} instead of 256-cy
//      single-pipe phases; V ds_reads issued before the exp2 chain.
//  launch_bounds(512,2): spill-safe (R1: forced 128-cap spilled 4.5GB);
//  R3 showed 8 vs 16 waves/CU is perf-neutral here.
__global__ __launch_bounds__(512, 2) void attn_fwd(const float* __restrict__ q,
                                                   const bf16* __restrict__ img,
                                                   float* __restrict__ out) {
    __shared__ __align__(16) bf16 KV[2][2][8192];  // [group][dbuf] 16 KB tiles
    __shared__ float EXL[4][64];                   // denominator partials per wave-pair

    const int tid  = threadIdx.x;
    const int lane = tid & 63;
    const int wv   = tid >> 6;          // 0..7
    const int grp  = wv >> 2;           // KV half: 0 -> tiles 0..15, 1 -> 16..31
    const int wp   = wv & 3;            // wave-pair id == q-subtile
    const int half = lane >> 5;
    const int l31  = lane & 31;

    const int bh = blockIdx.y;
    const int b  = bh >> 4;
    const int q0 = blockIdx.x * BM + wp * 32;

    const bf16* tiles = img + (size_t)b * 32 * 8192;

    // Q frags (B-layout for S^T: n=q=l31, k=d=ks*16+half*8+j), pre-scaled
    bf16x8 qf[4];
    #pragma unroll
    for (int ks = 0; ks < 4; ++ks) {
        const float* src = q + ((size_t)bh * N_ + q0 + l31) * D_ + ks * 16 + half * 8;
        float4 a = *(const float4*)src;
        float4 c = *(const float4*)(src + 4);
        bf16x8 pk;
        pk[0] = (bf16)(a.x * SCALE_LOG2E); pk[1] = (bf16)(a.y * SCALE_LOG2E);
        pk[2] = (bf16)(a.z * SCALE_LOG2E); pk[3] = (bf16)(a.w * SCALE_LOG2E);
        pk[4] = (bf16)(c.x * SCALE_LOG2E); pk[5] = (bf16)(c.y * SCALE_LOG2E);
        pk[6] = (bf16)(c.z * SCALE_LOG2E); pk[7] = (bf16)(c.w * SCALE_LOG2E);
        qf[ks] = pk;
    }

    // ones A-frag: 32x16 matrix of 1.0 -> every lane holds 8x bf16(1.0)
    bf16x8 ones;
    #pragma unroll
    for (int j = 0; j < 8; ++j) ones[j] = (bf16)1.0f;

    f32x16 acc[2] = {{}, {}};           // O^T tiles [mt_d] (unnormalized)
    f32x16 accL = {};                   // denominator (all rows identical)

    auto issue_dma = [&](int t, int p) {
        const bf16* g = tiles + (size_t)t * 8192;
        #pragma unroll
        for (int j = 0; j < 4; ++j) {
            const int c = wp * 4 + j;             // 1 KB chunk 0..15 within group's tile
            __builtin_amdgcn_global_load_lds(GBL(g + c * 512 + lane * 8),
                                             LDS(&KV[grp][p][c * 512]), 16, 0, 0);
        }
    };

    const int t0 = grp * 16;                      // first tile of this group's range
    issue_dma(t0, 0);

    for (int it = 0; it < 16; ++it) {
        const int p = it & 1;
        __syncthreads();                          // drains tile DMA; protects buf p^1
        if (it + 1 < 16) issue_dma(t0 + it + 1, p ^ 1);

        // S^T = K Q^T : two 32x32 kv-tiles, C col=q=l31, row=kv.
        // K frags loaded just-in-time (8 live regs, not 64 preloaded).
        f32x16 s[2] = {{}, {}};
        #pragma unroll
        for (int ks = 0; ks < 4; ++ks) {
            bf16x8 k0 = *(const bf16x8*)&KV[grp][p][((0 * 4 + ks) * 64 + lane) * 8];
            bf16x8 k1 = *(const bf16x8*)&KV[grp][p][((1 * 4 + ks) * 64 + lane) * 8];
            s[0] = __builtin_amdgcn_mfma_f32_32x32x16_bf16(k0, qf[ks], s[0], 0, 0, 0);
            s[1] = __builtin_amdgcn_mfma_f32_32x32x16_bf16(k1, qf[ks], s[1], 0, 0, 0);
        }
        #pragma unroll
        for (int mt = 0; mt < 2; ++mt) {
            #pragma unroll
            for (int sp = 0; sp < 2; ++sp) {
                const int g = mt * 2 + sp;        // kv k-step 0..3
                // V reads issued before the exp2 chain: LDS latency covered
                bf16x8 v0 = *(const bf16x8*)&KV[grp][p][4096 + ((0 * 4 + g) * 64 + lane) * 8];
                bf16x8 v1 = *(const bf16x8*)&KV[grp][p][4096 + ((1 * 4 + g) * 64 + lane) * 8];
                float pv8[8];
                #pragma unroll
                for (int r = 0; r < 8; ++r) pv8[r] = __builtin_amdgcn_exp2f(s[mt][8 * sp + r]);
                bf16x4 lo = pack4(pv8[0], pv8[1], pv8[2], pv8[3]);
                bf16x4 hi = pack4(pv8[4], pv8[5], pv8[6], pv8[7]);
                bf16x8 bfrag = cswap(lo, hi);
                accL   = __builtin_amdgcn_mfma_f32_32x32x16_bf16(ones, bfrag, accL, 0, 0, 0);
                acc[0] = __builtin_amdgcn_mfma_f32_32x32x16_bf16(v0, bfrag, acc[0], 0, 0, 0);
                acc[1] = __builtin_amdgcn_mfma_f32_32x32x16_bf16(v1, bfrag, acc[1], 0, 0, 0);
            }
        }
    }

    // ---- combine the two KV halves (wave wp <-> wave wp+4), reusing KV LDS ----
    __syncthreads();                              // all compute reads of KV done
    float* ex = (float*)&KV[0][0][0] + wp * 2048; // 8 KB exchange region per pair

    if (grp == 1) {
        #pragma unroll
        for (int mt = 0; mt < 2; ++mt)
            #pragma unroll
            for (int rq = 0; rq < 4; ++rq) {
                const int c = mt * 4 + rq;
                float4 v4;
                v4.x = acc[mt][4 * rq + 0];
                v4.y = acc[mt][4 * rq + 1];
                v4.z = acc[mt][4 * rq + 2];
                v4.w = acc[mt][4 * rq + 3];
                *(float4*)&ex[(c * 64 + lane) * 4] = v4;   // lane-contiguous, conflict-free
            }
        EXL[wp][lane] = accL[0];                  // full column sum (MFMA summed all rows)
    }
    __syncthreads();
    if (grp == 0) {
        float l = accL[0] + EXL[wp][lane];        // own half + partner half
        #pragma unroll
        for (int mt = 0; mt < 2; ++mt)
            #pragma unroll
            for (int rq = 0; rq < 4; ++rq) {
                const int c = mt * 4 + rq;
                float4 v4 = *(const float4*)&ex[(c * 64 + lane) * 4];
                acc[mt][4 * rq + 0] += v4.x;
                acc[mt][4 * rq + 1] += v4.y;
                acc[mt][4 * rq + 2] += v4.z;
                acc[mt][4 * rq + 3] += v4.w;
            }

        float inv = 1.0f / l;
        const int qrow = q0 + l31;
        float* dst = out + ((size_t)bh * N_ + qrow) * D_ + 4 * half;
        #pragma unroll
        for (int mt = 0; mt < 2; ++mt)
            #pragma unroll
            for (int rq = 0; rq < 4; ++rq) {
                float4 o;
                o.x = acc[mt][4 * rq + 0] * inv;
                o.y = acc[mt][4 * rq + 1] * inv;
                o.z = acc[mt][4 * rq + 2] * inv;
                o.w = acc[mt][4 * rq + 3] * inv;
                *(float4*)(dst + mt * 32 + 8 * rq) = o;   // d = mt*32 + 8*rq + 4*half
            }
    }
}

extern "C" void kernel_launch(void* const* d_in, const int* in_sizes, int n_in,
                              void* d_out, int out_size, void* d_ws, size_t ws_size,
                              hipStream_t stream) {
    const float* q = (const float*)d_in[0];
    const float* k = (const float*)d_in[1];
    const float* v = (const float*)d_in[2];
    float* out = (float*)d_out;

    bf16* img = (bf16*)d_ws;                      // 128 tiles x 16 KB = 2 MB

    convert_kv<<<B_ * 32, 512, 0, stream>>>(k, v, img);
    dim3 grid(N_ / BM, B_ * H_);
    attn_fwd<<<grid, 512, 0, stream>>>(q, img, out);
}

// Round 8
// 151.830 us; speedup vs baseline: 1.1052x; 1.0292x over previous
//
#include <hip/hip_runtime.h>
#include <hip/hip_bf16.h>

#define B_ 4
#define H_ 16
#define N_ 2048
#define D_ 64
#define BM 128   // q-rows per WG (32 per wave, 4 waves)

typedef __bf16 bf16;
typedef bf16 bf16x4 __attribute__((ext_vector_type(4)));
typedef bf16 bf16x8 __attribute__((ext_vector_type(8)));
typedef float f32x16 __attribute__((ext_vector_type(16)));
typedef unsigned u32x2 __attribute__((ext_vector_type(2)));
typedef unsigned u32x4 __attribute__((ext_vector_type(4)));

#define SCALE_LOG2E 0.18033688011112042f  // (1/sqrt(64)) * log2(e)

#define GBL(p) ((const __attribute__((address_space(1))) void*)(p))
#define LDS(p) ((__attribute__((address_space(3))) void*)(p))

// Per (b, kv-tile T of 64): 16 KB image in per-lane FRAGMENT ORDER for 32x32x16 MFMA.
//   K half  [0,8KB):  unit p=(mt*4+ks)*64+ln : A-frag K[kv=T*64+mt*32+(ln&31)][d=ks*16+(ln>>5)*8 ..+8]
//   V half  [8,16KB): unit p=(mt*4+ks)*64+ln : A-frag V^T[d=mt*32+(ln&31)][kv=T*64+ks*16+(ln>>5)*8 ..+8]
// V transpose via LDS: coalesced float4 row reads -> padded LDS -> fragment-order
// reads -> coalesced bf16x8 store. One block per tile.
__global__ __launch_bounds__(512) void convert_kv(const float* __restrict__ k,
                                                  const float* __restrict__ v,
                                                  bf16* __restrict__ img) {
    __shared__ bf16 VT[64][66];                   // stride 66 elems (132 B)
    const int tile = blockIdx.x;                  // b*32 + T
    const int b = tile >> 5, T = tile & 31;
    const int t = threadIdx.x;                    // 0..511 == unit id
    bf16* timg = img + (size_t)tile * 8192;       // 16 KB per tile

    const int mtks = t >> 6;
    const int ln   = t & 63;
    const int mt = mtks >> 2, ks = mtks & 3;

    // --- K half: direct, coalesced both sides ---
    {
        const int kvr = T * 64 + mt * 32 + (ln & 31);
        const int d0  = ks * 16 + (ln >> 5) * 8;
        const float* src = k + ((size_t)b * N_ + kvr) * D_ + d0;
        float4 a = *(const float4*)src;
        float4 c = *(const float4*)(src + 4);
        bf16x8 o;
        o[0] = (bf16)a.x; o[1] = (bf16)a.y; o[2] = (bf16)a.z; o[3] = (bf16)a.w;
        o[4] = (bf16)c.x; o[5] = (bf16)c.y; o[6] = (bf16)c.z; o[7] = (bf16)c.w;
        *(bf16x8*)(timg + t * 8) = o;
    }

    // --- V half phase 1: coalesced row load -> LDS bf16 ---
    {
        const int kv = t >> 3;                    // 0..63 (tile-local row)
        const int c8 = (t & 7) * 8;               // 0..56
        const float* src = v + ((size_t)b * N_ + T * 64 + kv) * D_ + c8;
        float4 a = *(const float4*)src;
        float4 c = *(const float4*)(src + 4);
        VT[kv][c8 + 0] = (bf16)a.x; VT[kv][c8 + 1] = (bf16)a.y;
        VT[kv][c8 + 2] = (bf16)a.z; VT[kv][c8 + 3] = (bf16)a.w;
        VT[kv][c8 + 4] = (bf16)c.x; VT[kv][c8 + 5] = (bf16)c.y;
        VT[kv][c8 + 6] = (bf16)c.z; VT[kv][c8 + 7] = (bf16)c.w;
    }
    __syncthreads();
    // --- V half phase 2: fragment-order read, coalesced store ---
    {
        const int d   = mt * 32 + (ln & 31);
        const int kv0 = ks * 16 + (ln >> 5) * 8;  // tile-local
        bf16x8 o;
        #pragma unroll
        for (int j = 0; j < 8; ++j) o[j] = VT[kv0 + j][d];
        *(bf16x8*)(timg + 4096 + t * 8) = o;
    }
}

static __device__ inline bf16x4 pack4(float a, float b, float c, float d) {
    bf16x4 r; r[0] = (bf16)a; r[1] = (bf16)b; r[2] = (bf16)c; r[3] = (bf16)d; return r;
}

// C->B half-wave exchange via v_permlane32_swap_b32. For (p,q) = swap(L,H):
//   p = {L.row0, H.row0}  == (half ? xhi : lo)
//   q = {L.row1, H.row1}  == (half ? hi  : xlo)
static __device__ inline bf16x8 cswap(bf16x4 lo, bf16x4 hi) {
    u32x2 l = __builtin_bit_cast(u32x2, lo);
    u32x2 h = __builtin_bit_cast(u32x2, hi);
    u32x2 r0 = __builtin_amdgcn_permlane32_swap(l[0], h[0], false, false);
    u32x2 r1 = __builtin_amdgcn_permlane32_swap(l[1], h[1], false, false);
    u32x4 o; o[0] = r0[0]; o[1] = r1[0]; o[2] = r0[1]; o[3] = r1[1];
    return __builtin_bit_cast(bf16x8, o);
}

// Flash attention, 32x32x16 MFMA, S^T/O^T orientation, P in registers.
//
// Round-8: ONE-TILE SOFTWARE PIPELINE. Nine variants (R0-R7) pinned at
// ~89-102 us with every pipe <45% busy; R7 proved +33% MFMA work is FREE.
// Diagnosis: in-order wave issue + exp2 DEPENDING on the S-MFMAs issued
// immediately before it exposes the full S-chain + softmax-chain latency
// serially every iteration, identically in all (phase-correlated) waves.
// Fix: iteration body = { S-MFMAs(tile t)  ||  softmax+PV(tile t-1) } —
// the exp2 block has no dependency on the just-issued MFMAs, so the wave
// issues S(t) and immediately proceeds; S(t) results are consumed a full
// iteration (~500 cy) later. Requires V(t-1) alive while DMA(t+1) is in
// flight -> 3-slot LDS ring (mod-3: read/write slots provably distinct).
// Group-split dropped (no combine epilogue); 4-wave blocks, 48 KB LDS ->
// 3 blocks/CU; sA/sB named s-regs (rule #20: no runtime-indexed reg arrays).
__global__ __launch_bounds__(256, 2) void attn_fwd(const float* __restrict__ q,
                                                   const bf16* __restrict__ img,
                                                   float* __restrict__ out) {
    __shared__ __align__(16) bf16 KV3[3][8192];   // 3-slot ring, 48 KB

    const int tid  = threadIdx.x;
    const int lane = tid & 63;
    const int wv   = tid >> 6;          // 0..3
    const int half = lane >> 5;
    const int l31  = lane & 31;

    const int bh = blockIdx.y;
    const int b  = bh >> 4;
    const int q0 = blockIdx.x * BM + wv * 32;

    const bf16* tiles = img + (size_t)b * 32 * 8192;

    // Q frags (B-layout for S^T: n=q=l31, k=d=ks*16+half*8+j), pre-scaled
    bf16x8 qf[4];
    #pragma unroll
    for (int ks = 0; ks < 4; ++ks) {
        const float* src = q + ((size_t)bh * N_ + q0 + l31) * D_ + ks * 16 + half * 8;
        float4 a = *(const float4*)src;
        float4 c = *(const float4*)(src + 4);
        bf16x8 pk;
        pk[0] = (bf16)(a.x * SCALE_LOG2E); pk[1] = (bf16)(a.y * SCALE_LOG2E);
        pk[2] = (bf16)(a.z * SCALE_LOG2E); pk[3] = (bf16)(a.w * SCALE_LOG2E);
        pk[4] = (bf16)(c.x * SCALE_LOG2E); pk[5] = (bf16)(c.y * SCALE_LOG2E);
        pk[6] = (bf16)(c.z * SCALE_LOG2E); pk[7] = (bf16)(c.w * SCALE_LOG2E);
        qf[ks] = pk;
    }

    f32x16 acc[2] = {{}, {}};           // O^T tiles [mt_d] (unnormalized)
    float lacc = 0.f;

    auto issue_dma = [&](int t, int sl) {
        const bf16* g = tiles + (size_t)t * 8192;
        #pragma unroll
        for (int j = 0; j < 4; ++j) {
            const int c = wv * 4 + j;             // 1 KB chunk 0..15
            __builtin_amdgcn_global_load_lds(GBL(g + c * 512 + lane * 8),
                                             LDS(&KV3[sl][c * 512]), 16, 0, 0);
        }
    };

    // S^T(tile it) = K Q^T into s: K frags JIT from ring slot it%3
    auto computeS = [&](int it, f32x16 (&s)[2]) {
        const bf16* bp = &KV3[it % 3][0];
        s[0] = f32x16{}; s[1] = f32x16{};
        #pragma unroll
        for (int ks = 0; ks < 4; ++ks) {
            bf16x8 k0 = *(const bf16x8*)&bp[((0 * 4 + ks) * 64 + lane) * 8];
            bf16x8 k1 = *(const bf16x8*)&bp[((1 * 4 + ks) * 64 + lane) * 8];
            s[0] = __builtin_amdgcn_mfma_f32_32x32x16_bf16(k0, qf[ks], s[0], 0, 0, 0);
            s[1] = __builtin_amdgcn_mfma_f32_32x32x16_bf16(k1, qf[ks], s[1], 0, 0, 0);
        }
    };
    // softmax + PV for tile it (V frags JIT from ring slot it%3)
    auto softpv = [&](int it, const f32x16 (&s)[2]) {
        const bf16* vp = &KV3[it % 3][4096];
        #pragma unroll
        for (int mt = 0; mt < 2; ++mt) {
            #pragma unroll
            for (int sp = 0; sp < 2; ++sp) {
                const int g = mt * 2 + sp;        // kv k-step 0..3
                bf16x8 v0 = *(const bf16x8*)&vp[((0 * 4 + g) * 64 + lane) * 8];
                bf16x8 v1 = *(const bf16x8*)&vp[((1 * 4 + g) * 64 + lane) * 8];
                float pv8[8];
                #pragma unroll
                for (int r = 0; r < 8; ++r) pv8[r] = __builtin_amdgcn_exp2f(s[mt][8 * sp + r]);
                lacc += ((pv8[0] + pv8[1]) + (pv8[2] + pv8[3]))
                      + ((pv8[4] + pv8[5]) + (pv8[6] + pv8[7]));
                bf16x4 lo = pack4(pv8[0], pv8[1], pv8[2], pv8[3]);
                bf16x4 hi = pack4(pv8[4], pv8[5], pv8[6], pv8[7]);
                bf16x8 bfrag = cswap(lo, hi);
                acc[0] = __builtin_amdgcn_mfma_f32_32x32x16_bf16(v0, bfrag, acc[0], 0, 0, 0);
                acc[1] = __builtin_amdgcn_mfma_f32_32x32x16_bf16(v1, bfrag, acc[1], 0, 0, 0);
            }
        }
    };

    f32x16 sA[2], sB[2];

    // prologue: fill slot 0, start slot 1, compute S(0)
    issue_dma(0, 0);
    __syncthreads();                              // DMA(0) complete
    issue_dma(1, 1);
    computeS(0, sA);

    // pipelined main loop: pairs (it, it+1) for it = 1,3,...,29
    #pragma unroll 1
    for (int it = 1; it < 31; it += 2) {
        __syncthreads();                          // DMA(it) complete; prev reads done
        issue_dma(it + 1, (it + 1) % 3);          // overwrites tile it-2 (consumed)
        computeS(it, sB);                         // MFMA pipe: S(it)
        softpv(it - 1, sA);                       // VALU/trans+MFMA: tile it-1
        __syncthreads();                          // DMA(it+1) complete
        issue_dma(it + 2, (it + 2) % 3);          // it+2 <= 31
        computeS(it + 1, sA);
        softpv(it, sB);
    }
    // tail: S(31) + softmax(30), then softmax(31)
    __syncthreads();                              // DMA(31) complete
    computeS(31, sB);
    softpv(30, sA);
    softpv(31, sB);

    // epilogue: denominator = own + partner half-wave partial; store float4
    float l = lacc + __shfl_xor(lacc, 32);
    float inv = 1.0f / l;
    const int qrow = q0 + l31;
    float* dst = out + ((size_t)bh * N_ + qrow) * D_ + 4 * half;
    #pragma unroll
    for (int mt = 0; mt < 2; ++mt)
        #pragma unroll
        for (int rq = 0; rq < 4; ++rq) {
            float4 o;
            o.x = acc[mt][4 * rq + 0] * inv;
            o.y = acc[mt][4 * rq + 1] * inv;
            o.z = acc[mt][4 * rq + 2] * inv;
            o.w = acc[mt][4 * rq + 3] * inv;
            *(float4*)(dst + mt * 32 + 8 * rq) = o;   // d = mt*32 + 8*rq + 4*half
        }
}

extern "C" void kernel_launch(void* const* d_in, const int* in_sizes, int n_in,
                              void* d_out, int out_size, void* d_ws, size_t ws_size,
                              hipStream_t stream) {
    const float* q = (const float*)d_in[0];
    const float* k = (const float*)d_in[1];
    const float* v = (const float*)d_in[2];
    float* out = (float*)d_out;

    bf16* img = (bf16*)d_ws;                      // 128 tiles x 16 KB = 2 MB

    convert_kv<<<B_ * 32, 512, 0, stream>>>(k, v, img);
    dim3 grid(N_ / BM, B_ * H_);
    attn_fwd<<<grid, 256, 0, stream>>>(q, img, out);
}